// Round 7
// baseline (117.609 us; speedup 1.0000x reference)
//
#include <hip/hip_runtime.h>

// GauntTensorProductFixedParity — R13: single launch; in-kernel frag gather.
//
// R12 (108.0 µs) = 82.4 µs harness fills + gaunt (~15-18) + precompute
// dispatch + 2 launch gaps. R13 removes the precompute kernel entirely:
// each block gathers its own lane's operand frags (W/Yf/Yw, ~104 VGPR)
// straight from the 39 KB L1/L2-hot tables with predicated scalar loads,
// placed between stage(0) and stage(1) so the gather latency hides under
// chunk-0's HBM wait (same slot the ws preload occupied in R12). The
// counted-vmcnt double-buffer pipeline, LDS swizzle, and MFMA chain are
// bit-identical to the passing R12.
//
// Pipeline (verified R12): 4 chunks x 64 rows, 2x32KB LDS double-buffer,
// global_load_lds(16B) staging, s_waitcnt vmcnt(8) + raw s_barrier between
// chunks (never drain mid-loop), stores deferred to the end.
// Compute chain (verified R9-R12):
//   stage 1 (16x16x32): c^T[s,row]  = sum_d W[d,s]·in[row,d]   (A=Wf, B=in)
//   stage 2 (16x16x16): G[p,row]    = sum_s Y[p,s]·c^T[s,row]  (A=Yf, B=c-chain)
//   H = G1 ⊙ G2 ; GEMM2 (16x16x16): out[s,row] += sum_p Yw^T[s,p]·H[p,row]
// Lane mappings (harness-verified R7-R12):
//   A/B-frag K=32: (idx = lane&15, k = quad*8+j)
//   A/B-frag K=16: (idx = lane&15, k = quad*4+i)
//   C/D:           (n = lane&15,   m = quad*4+i)
// LDS tile 16B-slot XOR swizzle (both-sides rule, verified R11/R12):
// logical (r,s) lives at (r, s ^ (r&7)); source pre-swizzled, dest linear.

typedef _Float16 f16x8 __attribute__((ext_vector_type(8)));
typedef _Float16 f16x4 __attribute__((ext_vector_type(4)));
typedef float f32x4 __attribute__((ext_vector_type(4)));
typedef float f32x4u __attribute__((ext_vector_type(4), aligned(4)));

namespace {
constexpr int kD = 64, kS = 25, kP = 132;
constexpr int kBlock = 256;
constexpr int kCh = 64;                  // rows per chunk (4 waves x 16 rows)
constexpr int kChunks = 4;               // 256 rows per block
}

__device__ __forceinline__ f16x8 cvt8h(f32x4 u, f32x4 v) {
    f16x8 r;
    r[0] = (_Float16)u[0]; r[1] = (_Float16)u[1];
    r[2] = (_Float16)u[2]; r[3] = (_Float16)u[3];
    r[4] = (_Float16)v[0]; r[5] = (_Float16)v[1];
    r[6] = (_Float16)v[2]; r[7] = (_Float16)v[3];
    return r;
}

__global__ __launch_bounds__(kBlock, 2) void gaunt_fused13(
    const float* __restrict__ in1, const float* __restrict__ in2,
    const float* __restrict__ W1, const float* __restrict__ W2,
    const float* __restrict__ Y,  const float* __restrict__ Yw,
    float* __restrict__ out)
{
    // [buf][op][row 64][slot 16] of f32x4, 16-B slots XOR-swizzled. 64 KB.
    __shared__ f32x4 ldsq[2][2][kCh][16];

    const int tid  = threadIdx.x;
    const int lane = tid & 63;
    const int w    = __builtin_amdgcn_readfirstlane(tid >> 6);
    const int lo16 = lane & 15, quad = lane >> 4;
    const long long rowbase = (long long)blockIdx.x * (kChunks * kCh);

    const int rg = lane >> 4;              // row within 4-row group
    const int sl = lane & 15;              // dest slot

    // Stage one 64-row x 2-op chunk into buffer `buf`: 8 global_load_lds(16B)
    // per wave; wave-uniform dest base, per-lane pre-swizzled SOURCE slot.
    auto stage = [&](int chunk, int buf) {
        #pragma unroll
        for (int i = 0; i < 8; ++i) {
            const int t  = w * 8 + i;      // 0..31
            const int op = t >> 4, q = t & 15;
            const int r  = q * 4 + rg;
            const int c16 = sl ^ (r & 7);  // source slot (inverse swizzle)
            const float* src = (op ? in2 : in1)
                + (rowbase + chunk * kCh + r) * kD + c16 * 4;
            char* dst = (char*)(&ldsq[buf][op][q * 4][0]);
            __builtin_amdgcn_global_load_lds(
                (const __attribute__((address_space(1))) void*)src,
                (__attribute__((address_space(3))) void*)dst,
                16, 0, 0);
        }
    };

    // ---- chunk 0 staging first ----
    stage(0, 0);

    // ---- in-kernel frag gather (replaces R12's ws preload; hides under
    //      chunk-0 HBM latency). Mappings identical to R12's precompute. ----
    // Wf(op,st,ks): A(m = s = st*16+lo16, k = d = ks*32+quad*8+j)
    f16x8 wf[2][2][2];                     // [op][st][ks]
    #pragma unroll
    for (int op = 0; op < 2; ++op) {
        const float* W = op ? W2 : W1;
        #pragma unroll
        for (int st = 0; st < 2; ++st) {
            const int s = st * 16 + lo16;
            #pragma unroll
            for (int ks = 0; ks < 2; ++ks) {
                const int d0 = ks * 32 + quad * 8;
                f16x8 a;
                #pragma unroll
                for (int j = 0; j < 8; ++j)
                    a[j] = (s < kS) ? (_Float16)W[(d0 + j) * kS + s]
                                    : (_Float16)0.f;
                wf[op][st][ks] = a;
            }
        }
    }
    // Yf(pt,st): A(m = p = pt*16+lo16, k = s = st*16+quad*4+i)
    // Ywt(st,pt): A(m = s = st*16+lo16, k = p = pt*16+quad*4+i)
    f16x4 yf[9][2], yw[2][9];
    #pragma unroll
    for (int pt = 0; pt < 9; ++pt) {
        const int p = pt * 16 + lo16;
        #pragma unroll
        for (int st = 0; st < 2; ++st) {
            f16x4 v;
            #pragma unroll
            for (int i = 0; i < 4; ++i) {
                const int s = st * 16 + quad * 4 + i;
                v[i] = (p < kP && s < kS) ? (_Float16)Y[p * kS + s]
                                          : (_Float16)0.f;
            }
            yf[pt][st] = v;
        }
        #pragma unroll
        for (int st = 0; st < 2; ++st) {
            const int s = st * 16 + lo16;
            f16x4 v;
            #pragma unroll
            for (int i = 0; i < 4; ++i) {
                const int p2 = pt * 16 + quad * 4 + i;
                v[i] = (s < kS && p2 < kP) ? (_Float16)Yw[p2 * kS + s]
                                           : (_Float16)0.f;
            }
            yw[st][pt] = v;
        }
    }

    // ---- chunk 1 prefetch (stays in flight across chunk 0 compute) ----
    stage(1, 1);

    const int r  = w * 16 + lo16;          // local row this lane consumes
    const int r7 = lo16 & 7;               // (w*16+lo16)&7 == lo16&7

    f32x4 o0[kChunks], o1[kChunks];
    #pragma unroll
    for (int c = 0; c < kChunks; ++c) {
        o0[c] = (f32x4){0.f, 0.f, 0.f, 0.f};
        o1[c] = (f32x4){0.f, 0.f, 0.f, 0.f};
    }

    // Compute one chunk from LDS buffer `buf` into (o0c, o1c). Zero loads in
    // the pt loop: frags are register-resident, loop fully unrolled.
    auto compute = [&](int buf, f32x4& o0c, f32x4& o1c) {
        f16x8 b[2][2];                     // [op][ks]
        #pragma unroll
        for (int op = 0; op < 2; ++op)
            #pragma unroll
            for (int ks = 0; ks < 2; ++ks) {
                const int s0 = ks * 8 + quad * 2;
                const f32x4 u = ldsq[buf][op][r][s0 ^ r7];
                const f32x4 v = ldsq[buf][op][r][(s0 + 1) ^ r7];
                b[op][ks] = cvt8h(u, v);
            }
        f16x4 h1[2], h2[2];                // [st] chain B-frags (n=row, k=s)
        #pragma unroll
        for (int st = 0; st < 2; ++st) {
            f32x4 c1 = (f32x4){0.f, 0.f, 0.f, 0.f};
            f32x4 c2 = (f32x4){0.f, 0.f, 0.f, 0.f};
            #pragma unroll
            for (int ks = 0; ks < 2; ++ks) {
                c1 = __builtin_amdgcn_mfma_f32_16x16x32_f16(wf[0][st][ks], b[0][ks], c1, 0, 0, 0);
                c2 = __builtin_amdgcn_mfma_f32_16x16x32_f16(wf[1][st][ks], b[1][ks], c2, 0, 0, 0);
            }
            #pragma unroll
            for (int i = 0; i < 4; ++i) {
                h1[st][i] = (_Float16)c1[i];
                h2[st][i] = (_Float16)c2[i];
            }
        }
        #pragma unroll
        for (int pt = 0; pt < 9; ++pt) {
            const f32x4 z = (f32x4){0.f, 0.f, 0.f, 0.f};
            f32x4 g1 = __builtin_amdgcn_mfma_f32_16x16x16f16(yf[pt][0], h1[0], z, 0, 0, 0);
            g1       = __builtin_amdgcn_mfma_f32_16x16x16f16(yf[pt][1], h1[1], g1, 0, 0, 0);
            f32x4 g2 = __builtin_amdgcn_mfma_f32_16x16x16f16(yf[pt][0], h2[0], z, 0, 0, 0);
            g2       = __builtin_amdgcn_mfma_f32_16x16x16f16(yf[pt][1], h2[1], g2, 0, 0, 0);
            f16x4 h;
            h[0] = (_Float16)(g1[0] * g2[0]);
            h[1] = (_Float16)(g1[1] * g2[1]);
            h[2] = (_Float16)(g1[2] * g2[2]);
            h[3] = (_Float16)(g1[3] * g2[3]);
            o0c = __builtin_amdgcn_mfma_f32_16x16x16f16(yw[0][pt], h, o0c, 0, 0, 0);
            o1c = __builtin_amdgcn_mfma_f32_16x16x16f16(yw[1][pt], h, o1c, 0, 0, 0);
        }
    };

    // ---- pipelined chunk sequence: counted vmcnt, never drain mid-loop ----
    // waitcnt(8) leaves the newest 8 loads (next chunk's prefetch) in
    // flight; per-wave waitcnt + barrier => all waves' current-chunk loads
    // (and all frag gathers, which are older) have landed.
    asm volatile("s_waitcnt vmcnt(8)" ::: "memory");
    __builtin_amdgcn_s_barrier();
    compute(0, o0[0], o1[0]);
    __builtin_amdgcn_s_barrier();          // buf0 free
    stage(2, 0);
    asm volatile("s_waitcnt vmcnt(8)" ::: "memory");
    __builtin_amdgcn_s_barrier();
    compute(1, o0[1], o1[1]);
    __builtin_amdgcn_s_barrier();          // buf1 free
    stage(3, 1);
    asm volatile("s_waitcnt vmcnt(8)" ::: "memory");
    __builtin_amdgcn_s_barrier();
    compute(0, o0[2], o1[2]);
    asm volatile("s_waitcnt vmcnt(0)" ::: "memory");
    __builtin_amdgcn_s_barrier();
    compute(1, o0[3], o1[3]);

    // ---- stores: out^T C-layout (n=row, m=s) -> 16B runs ----
    #pragma unroll
    for (int c = 0; c < kChunks; ++c) {
        const long long row = rowbase + c * kCh + r;
        float* rp = out + row * kS;
        *reinterpret_cast<f32x4u*>(rp + quad * 4) = o0[c];
        if (quad < 2) {
            *reinterpret_cast<f32x4u*>(rp + 16 + quad * 4) = o1[c];
        } else if (quad == 2) {
            rp[24] = o1[c][0];
        }
    }
}

extern "C" void kernel_launch(void* const* d_in, const int* in_sizes, int n_in,
                              void* d_out, int out_size, void* d_ws, size_t ws_size,
                              hipStream_t stream) {
    const float* in1 = (const float*)d_in[0];   // [N, 64]
    const float* in2 = (const float*)d_in[1];   // [N, 64]
    const float* W1  = (const float*)d_in[2];   // [64, 25]
    const float* W2  = (const float*)d_in[3];   // [64, 25]
    const float* Y   = (const float*)d_in[4];   // [132, 25]
    const float* Yw  = (const float*)d_in[5];   // [132, 25]
    float* out = (float*)d_out;                 // [N, 25]
    (void)d_ws; (void)ws_size;

    const int n_rows = in_sizes[0] / kD;        // 131072
    const int grid = n_rows / (kChunks * kCh);  // 512 blocks, 2/CU
    gaunt_fused13<<<grid, kBlock, 0, stream>>>(in1, in2, W1, W2, Y, Yw, out);
}

// Round 8
// 108.992 us; speedup vs baseline: 1.0791x; 1.0791x over previous
//
#include <hip/hip_runtime.h>

// GauntTensorProductFixedParity — R14: revert to R12 (measured best, 108.0 µs).
//
// R13's in-kernel frag gather regressed (+9.6 µs): ~180 scalar VMEM insts
// per lane, all FIFO-older than the chunk-1 prefetch, forced to drain by the
// first vmcnt(8) — a serial issue-bound prologue per block. R12's structure
// (one-shot pure-swizzle precompute into ws; hot kernel does ~30 VECTOR frag
// loads) is the right division of labor. This file is the R12 winner.
//
// Pipeline: 4 chunks x 64 rows/block, 2x32KB LDS double-buffer staged with
// global_load_lds(16B); counted s_waitcnt vmcnt(8) + raw s_barrier between
// chunks (never drain mid-loop); ALL operand frags (W/Yf/Yw) preloaded to
// registers, pt-loop fully unrolled (zero loads inside); stores deferred to
// the end so vmcnt counts only loads. LDS 64KB -> 2 blocks/CU x 4 waves =
// 8 waves/CU; grid 512 (fully co-resident).
//
// Compute chain (harness-verified R9-R12):
//   stage 1 (16x16x32): c^T[s,row]  = sum_d W[d,s]·in[row,d]   (A=Wf, B=in)
//   stage 2 (16x16x16): G[p,row]    = sum_s Y[p,s]·c^T[s,row]  (A=Yf, B=c-chain)
//   H = G1 ⊙ G2 ; GEMM2 (16x16x16): out[s,row] += sum_p Yw^T[s,p]·H[p,row]
// Lane mappings (harness-verified R7-R12):
//   A/B-frag K=32: (idx = lane&15, k = quad*8+j)
//   A/B-frag K=16: (idx = lane&15, k = quad*4+i)
//   C/D:           (n = lane&15,   m = quad*4+i)
// LDS tile 16B-slot XOR swizzle (both-sides rule, verified R11/R12):
// logical (r,s) lives at (r, s ^ (r&7)); source pre-swizzled, dest linear.

typedef _Float16 f16x8 __attribute__((ext_vector_type(8)));
typedef _Float16 f16x4 __attribute__((ext_vector_type(4)));
typedef float f32x4 __attribute__((ext_vector_type(4)));
typedef float f32x4u __attribute__((ext_vector_type(4), aligned(4)));

namespace {
constexpr int kD = 64, kS = 25, kP = 132;
constexpr int kBlock = 256;
constexpr int kCh = 64;                  // rows per chunk (4 waves x 16 rows)
constexpr int kChunks = 4;               // 256 rows per block
// ws layout (halfs):
constexpr int kYfOff = 0;                // Yf  [pt9][st2][64][4] = 4608
constexpr int kYwOff = 4608;             // Ywt [st2][pt9][64][4] = 4608
constexpr int kWfOff = 9216;             // Wf  [op2][st2][ks2][64][8] = 4096
constexpr int kWsHalfs = 13312;          // 26624 B
}

// ---- Precompute: pure-swizzle frag tables (no FMA) ----
__global__ void precompute14(const float* __restrict__ W1,
                             const float* __restrict__ W2,
                             const float* __restrict__ Y,
                             const float* __restrict__ Yw,
                             _Float16* __restrict__ ws) {
    const int e = blockIdx.x * blockDim.x + threadIdx.x;
    if (e < 4608) {
        // Yf(pt,st): A(m = p = pt*16+lo16, k = s = st*16+quad*4+i)
        const int i = e & 3, ln = (e >> 2) & 63, r = e >> 8;   // r 0..17
        const int pt = r >> 1, st = r & 1;
        const int p = pt * 16 + (ln & 15);
        const int s = st * 16 + ((ln >> 4) & 3) * 4 + i;
        ws[kYfOff + e] = (s < kS && p < kP) ? (_Float16)Y[p * kS + s]
                                            : (_Float16)0.f;
    } else if (e < 9216) {
        // Ywt(st,pt): A(m = s = st*16+lo16, k = p = pt*16+quad*4+i)
        const int e2 = e - 4608;
        const int i = e2 & 3, ln = (e2 >> 2) & 63, r = e2 >> 8; // r 0..17
        const int pt = r % 9, st = r / 9;
        const int p = pt * 16 + ((ln >> 4) & 3) * 4 + i;
        const int s = st * 16 + (ln & 15);
        ws[kYwOff + e2] = (s < kS && p < kP) ? (_Float16)Yw[p * kS + s]
                                             : (_Float16)0.f;
    } else if (e < kWsHalfs) {
        // Wf(op,st,ks): A(m = s = st*16+lo16, k = d = ks*32+quad*8+j)
        const int e3 = e - 9216;
        const int j = e3 & 7, ln = (e3 >> 3) & 63, r = e3 >> 9; // r 0..7
        const int ks = r & 1, st = (r >> 1) & 1, op = r >> 2;
        const int s = st * 16 + (ln & 15);
        const int d = ks * 32 + ((ln >> 4) & 3) * 8 + j;
        const float* W = op ? W2 : W1;
        ws[kWfOff + e3] = (s < kS) ? (_Float16)W[d * kS + s] : (_Float16)0.f;
    }
}

__device__ __forceinline__ f16x8 ld8(const _Float16* p) {
    return *reinterpret_cast<const f16x8*>(p);
}
__device__ __forceinline__ f16x4 ld4(const _Float16* p) {
    return *reinterpret_cast<const f16x4*>(p);
}
__device__ __forceinline__ f16x8 cvt8h(f32x4 u, f32x4 v) {
    f16x8 r;
    r[0] = (_Float16)u[0]; r[1] = (_Float16)u[1];
    r[2] = (_Float16)u[2]; r[3] = (_Float16)u[3];
    r[4] = (_Float16)v[0]; r[5] = (_Float16)v[1];
    r[6] = (_Float16)v[2]; r[7] = (_Float16)v[3];
    return r;
}

__global__ __launch_bounds__(kBlock, 2) void gaunt_fused14(
    const float* __restrict__ in1, const float* __restrict__ in2,
    const _Float16* __restrict__ ws, float* __restrict__ out)
{
    // [buf][op][row 64][slot 16] of f32x4, 16-B slots XOR-swizzled. 64 KB.
    __shared__ f32x4 ldsq[2][2][kCh][16];

    const int tid  = threadIdx.x;
    const int lane = tid & 63;
    const int w    = __builtin_amdgcn_readfirstlane(tid >> 6);
    const int lo16 = lane & 15, quad = lane >> 4;
    const long long rowbase = (long long)blockIdx.x * (kChunks * kCh);

    const int rg = lane >> 4;              // row within 4-row group
    const int sl = lane & 15;              // dest slot

    // Stage one 64-row x 2-op chunk into buffer `buf`: 8 global_load_lds(16B)
    // per wave; wave-uniform dest base, per-lane pre-swizzled SOURCE slot.
    auto stage = [&](int chunk, int buf) {
        #pragma unroll
        for (int i = 0; i < 8; ++i) {
            const int t  = w * 8 + i;      // 0..31
            const int op = t >> 4, q = t & 15;
            const int r  = q * 4 + rg;
            const int c16 = sl ^ (r & 7);  // source slot (inverse swizzle)
            const float* src = (op ? in2 : in1)
                + (rowbase + chunk * kCh + r) * kD + c16 * 4;
            char* dst = (char*)(&ldsq[buf][op][q * 4][0]);
            __builtin_amdgcn_global_load_lds(
                (const __attribute__((address_space(1))) void*)src,
                (__attribute__((address_space(3))) void*)dst,
                16, 0, 0);
        }
    };

    // ---- chunk 0 staging first ----
    stage(0, 0);

    // ---- preload ALL operand frags into registers (overlaps c0 latency) ----
    const _Float16* wsYf = ws + kYfOff;
    const _Float16* wsYw = ws + kYwOff;
    const _Float16* wsWf = ws + kWfOff;

    f16x8 wf[2][2][2];                     // [op][st][ks]
    #pragma unroll
    for (int op = 0; op < 2; ++op)
        #pragma unroll
        for (int st = 0; st < 2; ++st)
            #pragma unroll
            for (int ks = 0; ks < 2; ++ks)
                wf[op][st][ks] = ld8(&wsWf[((op * 2 + st) * 2 + ks) * 512 + lane * 8]);

    f16x4 yf[9][2], yw[2][9];
    #pragma unroll
    for (int pt = 0; pt < 9; ++pt) {
        yf[pt][0] = ld4(&wsYf[(pt * 2 + 0) * 256 + lane * 4]);
        yf[pt][1] = ld4(&wsYf[(pt * 2 + 1) * 256 + lane * 4]);
        yw[0][pt] = ld4(&wsYw[(0 * 9 + pt) * 256 + lane * 4]);
        yw[1][pt] = ld4(&wsYw[(1 * 9 + pt) * 256 + lane * 4]);
    }

    // ---- chunk 1 prefetch (stays in flight across chunk 0 compute) ----
    stage(1, 1);

    const int r  = w * 16 + lo16;          // local row this lane consumes
    const int r7 = lo16 & 7;               // (w*16+lo16)&7 == lo16&7

    f32x4 o0[kChunks], o1[kChunks];
    #pragma unroll
    for (int c = 0; c < kChunks; ++c) {
        o0[c] = (f32x4){0.f, 0.f, 0.f, 0.f};
        o1[c] = (f32x4){0.f, 0.f, 0.f, 0.f};
    }

    // Compute one chunk from LDS buffer `buf` into (o0c, o1c). Zero loads in
    // the pt loop: frags are register-resident, loop fully unrolled.
    auto compute = [&](int buf, f32x4& o0c, f32x4& o1c) {
        f16x8 b[2][2];                     // [op][ks]
        #pragma unroll
        for (int op = 0; op < 2; ++op)
            #pragma unroll
            for (int ks = 0; ks < 2; ++ks) {
                const int s0 = ks * 8 + quad * 2;
                const f32x4 u = ldsq[buf][op][r][s0 ^ r7];
                const f32x4 v = ldsq[buf][op][r][(s0 + 1) ^ r7];
                b[op][ks] = cvt8h(u, v);
            }
        f16x4 h1[2], h2[2];                // [st] chain B-frags (n=row, k=s)
        #pragma unroll
        for (int st = 0; st < 2; ++st) {
            f32x4 c1 = (f32x4){0.f, 0.f, 0.f, 0.f};
            f32x4 c2 = (f32x4){0.f, 0.f, 0.f, 0.f};
            #pragma unroll
            for (int ks = 0; ks < 2; ++ks) {
                c1 = __builtin_amdgcn_mfma_f32_16x16x32_f16(wf[0][st][ks], b[0][ks], c1, 0, 0, 0);
                c2 = __builtin_amdgcn_mfma_f32_16x16x32_f16(wf[1][st][ks], b[1][ks], c2, 0, 0, 0);
            }
            #pragma unroll
            for (int i = 0; i < 4; ++i) {
                h1[st][i] = (_Float16)c1[i];
                h2[st][i] = (_Float16)c2[i];
            }
        }
        #pragma unroll
        for (int pt = 0; pt < 9; ++pt) {
            const f32x4 z = (f32x4){0.f, 0.f, 0.f, 0.f};
            f32x4 g1 = __builtin_amdgcn_mfma_f32_16x16x16f16(yf[pt][0], h1[0], z, 0, 0, 0);
            g1       = __builtin_amdgcn_mfma_f32_16x16x16f16(yf[pt][1], h1[1], g1, 0, 0, 0);
            f32x4 g2 = __builtin_amdgcn_mfma_f32_16x16x16f16(yf[pt][0], h2[0], z, 0, 0, 0);
            g2       = __builtin_amdgcn_mfma_f32_16x16x16f16(yf[pt][1], h2[1], g2, 0, 0, 0);
            f16x4 h;
            h[0] = (_Float16)(g1[0] * g2[0]);
            h[1] = (_Float16)(g1[1] * g2[1]);
            h[2] = (_Float16)(g1[2] * g2[2]);
            h[3] = (_Float16)(g1[3] * g2[3]);
            o0c = __builtin_amdgcn_mfma_f32_16x16x16f16(yw[0][pt], h, o0c, 0, 0, 0);
            o1c = __builtin_amdgcn_mfma_f32_16x16x16f16(yw[1][pt], h, o1c, 0, 0, 0);
        }
    };

    // ---- pipelined chunk sequence: counted vmcnt, never drain mid-loop ----
    // waitcnt(8) before each barrier leaves the newest 8 loads (next chunk's
    // prefetch) in flight; per-wave waitcnt + barrier => all waves' loads for
    // the current chunk have landed.
    asm volatile("s_waitcnt vmcnt(8)" ::: "memory");
    __builtin_amdgcn_s_barrier();
    compute(0, o0[0], o1[0]);
    __builtin_amdgcn_s_barrier();          // buf0 free
    stage(2, 0);
    asm volatile("s_waitcnt vmcnt(8)" ::: "memory");
    __builtin_amdgcn_s_barrier();
    compute(1, o0[1], o1[1]);
    __builtin_amdgcn_s_barrier();          // buf1 free
    stage(3, 1);
    asm volatile("s_waitcnt vmcnt(8)" ::: "memory");
    __builtin_amdgcn_s_barrier();
    compute(0, o0[2], o1[2]);
    asm volatile("s_waitcnt vmcnt(0)" ::: "memory");
    __builtin_amdgcn_s_barrier();
    compute(1, o0[3], o1[3]);

    // ---- stores: out^T C-layout (n=row, m=s) -> 16B runs ----
    #pragma unroll
    for (int c = 0; c < kChunks; ++c) {
        const long long row = rowbase + c * kCh + r;
        float* rp = out + row * kS;
        *reinterpret_cast<f32x4u*>(rp + quad * 4) = o0[c];
        if (quad < 2) {
            *reinterpret_cast<f32x4u*>(rp + 16 + quad * 4) = o1[c];
        } else if (quad == 2) {
            rp[24] = o1[c][0];
        }
    }
}

extern "C" void kernel_launch(void* const* d_in, const int* in_sizes, int n_in,
                              void* d_out, int out_size, void* d_ws, size_t ws_size,
                              hipStream_t stream) {
    const float* in1 = (const float*)d_in[0];   // [N, 64]
    const float* in2 = (const float*)d_in[1];   // [N, 64]
    const float* W1  = (const float*)d_in[2];   // [64, 25]
    const float* W2  = (const float*)d_in[3];   // [64, 25]
    const float* Y   = (const float*)d_in[4];   // [132, 25]
    const float* Yw  = (const float*)d_in[5];   // [132, 25]
    float* out = (float*)d_out;                 // [N, 25]
    _Float16* ws = (_Float16*)d_ws;             // 13312 halfs used

    precompute14<<<52, 256, 0, stream>>>(W1, W2, Y, Yw, ws);

    const int n_rows = in_sizes[0] / kD;        // 131072
    const int grid = n_rows / (kChunks * kCh);  // 512 blocks, 2/CU
    gaunt_fused14<<<grid, kBlock, 0, stream>>>(in1, in2, ws, out);
}